// Round 3
// 1859.121 us; speedup vs baseline: 1.5733x; 1.5733x over previous
//
#include <hip/hip_runtime.h>
#include <hip/hip_bf16.h>

#define BB 4
#define CC 64
#define HH 96
#define WW 384
#define HW (HH*WW)          // 36864
#define CHW (CC*HW)         // 2359296
#define BH (BB*HH)          // 384
#define EPSV 1e-6f
#define QSCALE 0.125f       // C^-0.5, folded into Q_l

typedef __hip_bfloat16 bf16;
typedef short s8vec __attribute__((ext_vector_type(8)));   // 8 bf16 = one MFMA frag
typedef float f4vec __attribute__((ext_vector_type(4)));   // MFMA accum

__device__ __forceinline__ float b2f(bf16 v){ return __bfloat162float(v); }
__device__ __forceinline__ bf16 f2b(float v){ return __float2bfloat16(v); }
__device__ __forceinline__ unsigned short f2bu(float f){
    bf16 h = __float2bfloat16(f);
    return __builtin_bit_cast(unsigned short, h);
}

// ---------------- workspace layout (per-batch chunk) ----------------
// buf0: A [HH][WW][WW] bf16  -> overwritten in-place by P = M_r2l
// buf1: LT = M_l2r^T  bf16   (LT[u][v] = M_l2r[v][u])
// buf2: PT = P^T      bf16
//       * before k_trans, buf2 doubles as Ql/Qr/Vl/Vr (4*QELEMS <= ACHUNK);
//         k5m (V consumer) is ordered BEFORE k_trans so nothing is clobbered live.
// then f32 stats: rmax, irsum, cmax, icsum, mask_r2l, mask_l2r (each BH*WW)
// then 4 doubles.  TOTAL footprint identical to the verified baseline session.
#define ACHUNK ((size_t)HH*WW*WW)    // 14,155,776 elems
#define SST ((size_t)BH*WW)          // 147456
#define QELEMS ((size_t)HW*64)       // 2,359,296

// ---------------- K0: zero loss accumulators ----------------
__global__ void k0_zero(double* dsum){
    if (threadIdx.x < 4) dsum[threadIdx.x] = 0.0;
}

// ---------------- K_qv: LN + proj1 -> Q (bf16), proj2 -> V (bf16) ----------------
// grid (6 wtiles, HH), block 256. Computes BOTH sides; each pixel's Q/V computed ONCE
// (the old k2f recomputed Q_r 6x and k5f recomputed V 6x).
// Q layout: Q[(l*WW + w)*64 + c]   (c contiguous -> MFMA operand rows, K=c)
// V layout: V[c*HW + l*WW + v]     (v contiguous -> MFMA A operand rows, K=v)
__global__ __launch_bounds__(256) void k_qv(
    const float* __restrict__ xl, const float* __restrict__ xr,
    const float* __restrict__ nlw, const float* __restrict__ nlb,
    const float* __restrict__ nrw, const float* __restrict__ nrb,
    const float* __restrict__ P1l, const float* __restrict__ b1l,
    const float* __restrict__ P1r, const float* __restrict__ b1r,
    const float* __restrict__ P2l, const float* __restrict__ b2l,
    const float* __restrict__ P2r, const float* __restrict__ b2r,
    bf16* __restrict__ Ql, bf16* __restrict__ Qr,
    bf16* __restrict__ Vl, bf16* __restrict__ Vr, int b)
{
    __shared__ float xs[64*64];                  // [c][w]
    __shared__ float p1s[64*65], p2s[64*65];     // [o][c]
    __shared__ float nws[64], nbs[64], b1s[64], b2s[64];
    __shared__ float mus[64], ris[64];
    int t = threadIdx.x;
    int wt = blockIdx.x, l = blockIdx.y;
    int w0 = wt*64;

    for (int side=0; side<2; side++){
        const float* x  = side ? xr  : xl;
        const float* nw = side ? nrw : nlw;
        const float* nb = side ? nrb : nlb;
        const float* P1 = side ? P1r : P1l;
        const float* B1 = side ? b1r : b1l;
        const float* P2 = side ? P2r : P2l;
        const float* B2 = side ? b2r : b2l;
        bf16* Q = side ? Qr : Ql;
        bf16* V = side ? Vr : Vl;
        float qsc = side ? 1.f : QSCALE;

        if (t < 64){ nws[t]=nw[t]; nbs[t]=nb[t]; b1s[t]=B1[t]; b2s[t]=B2[t]; }
        for (int k=0;k<16;k++){
            int i=t+256*k; int o=i>>6, c=i&63;
            p1s[o*65+c]=P1[i]; p2s[o*65+c]=P2[i];
        }
        const float* xb = x + (size_t)b*CHW + (size_t)l*WW + w0;
        for (int k=0;k<16;k++){
            int c=(t>>6)+4*k, w=t&63;
            xs[c*64+w] = xb[(size_t)c*HW + w];
        }
        __syncthreads();
        if (t < 64){
            float s=0.f, ss=0.f;
            for (int c=0;c<64;c++){ float v=xs[c*64+t]; s+=v; ss+=v*v; }
            float mu=s*(1.f/64.f), var=ss*(1.f/64.f)-mu*mu;
            mus[t]=mu; ris[t]=rsqrtf(var+EPSV);
        }
        __syncthreads();

        // V projection (raw x): thread -> c-quad (t>>4)*4, v-quad (t&15)*4
        {
            int vq=t&15, ov=t>>4;
            float acc[4][4]={};
            for (int c=0;c<64;c++){
                float xv[4];
                for (int j=0;j<4;j++) xv[j]=xs[c*64+vq*4+j];
                for (int i=0;i<4;i++){
                    float w2=p2s[(ov*4+i)*65+c];
                    for (int j=0;j<4;j++) acc[i][j]+=w2*xv[j];
                }
            }
            for (int i=0;i<4;i++){
                int c=ov*4+i;
                ushort4 pk;
                pk.x=f2bu(acc[i][0]+b2s[c]); pk.y=f2bu(acc[i][1]+b2s[c]);
                pk.z=f2bu(acc[i][2]+b2s[c]); pk.w=f2bu(acc[i][3]+b2s[c]);
                *reinterpret_cast<ushort4*>(&V[(size_t)c*HW + (size_t)l*WW + w0 + vq*4]) = pk;
            }
        }
        // Q projection (LN'd x): thread -> c-quad (t&15)*4, w-quad (t>>4)*4
        {
            int cq=t&15, wq=t>>4;
            float muj[4], rij[4];
            for (int j=0;j<4;j++){ muj[j]=mus[wq*4+j]; rij[j]=ris[wq*4+j]; }
            float acc[4][4]={};
            for (int c=0;c<64;c++){
                float nwc=nws[c], nbc=nbs[c];
                float xn[4];
                for (int j=0;j<4;j++) xn[j]=(xs[c*64+wq*4+j]-muj[j])*rij[j]*nwc+nbc;
                for (int i=0;i<4;i++){
                    float w1=p1s[(cq*4+i)*65+c];
                    for (int j=0;j<4;j++) acc[i][j]+=w1*xn[j];
                }
            }
            for (int j=0;j<4;j++){
                int w=w0+wq*4+j;
                ushort4 pk;
                pk.x=f2bu(qsc*(acc[0][j]+b1s[cq*4+0]));
                pk.y=f2bu(qsc*(acc[1][j]+b1s[cq*4+1]));
                pk.z=f2bu(qsc*(acc[2][j]+b1s[cq*4+2]));
                pk.w=f2bu(qsc*(acc[3][j]+b1s[cq*4+3]));
                *reinterpret_cast<ushort4*>(&Q[((size_t)l*WW + w)*64 + cq*4]) = pk;
            }
        }
        __syncthreads();   // LDS reuse by next side
    }
}

// ---------------- K_attn: A = Q_l^T Q_r via MFMA ----------------
// grid (3 mt, 3 nt, HH), block 256 (4 waves; each wave one 64x64 quadrant of 128x128)
// A[w][v] = sum_c Ql[w][c] * Qr[v][c]   (K = 64, both operands c-contiguous)
__global__ __launch_bounds__(256) void k_attn(
    const bf16* __restrict__ Ql, const bf16* __restrict__ Qr,
    bf16* __restrict__ Abuf)
{
    __shared__ bf16 As[128*72];   // [w-row][c], stride 72 (144B: 2-way bank alias = free)
    __shared__ bf16 Bs[128*72];   // [v-row][c]
    int t=threadIdx.x;
    int mt=blockIdx.x, nt=blockIdx.y, l=blockIdx.z;
    const bf16* Qa = Ql + ((size_t)l*WW + mt*128)*64;
    const bf16* Qb = Qr + ((size_t)l*WW + nt*128)*64;
    for (int i=0;i<4;i++){
        int lin=t+256*i;            // 0..1023 over 128 rows x 8 chunks
        int r=lin>>3, c8=lin&7;
        *reinterpret_cast<uint4*>(&As[r*72+c8*8]) =
            *reinterpret_cast<const uint4*>(&Qa[(size_t)r*64 + c8*8]);
        *reinterpret_cast<uint4*>(&Bs[r*72+c8*8]) =
            *reinterpret_cast<const uint4*>(&Qb[(size_t)r*64 + c8*8]);
    }
    __syncthreads();
    int wv=t>>6, lane=t&63;
    int m0=(wv>>1)*64, n0=(wv&1)*64;
    int ln=lane&15, cq=lane>>4;
    f4vec acc[4][4];
    #pragma unroll
    for (int m=0;m<4;m++)
        #pragma unroll
        for (int n=0;n<4;n++) acc[m][n]=(f4vec){0.f,0.f,0.f,0.f};
    #pragma unroll
    for (int kk=0;kk<2;kk++){
        s8vec a[4], bb[4];
        #pragma unroll
        for (int m=0;m<4;m++) a[m]=*reinterpret_cast<const s8vec*>(&As[(m0+m*16+ln)*72 + kk*32 + cq*8]);
        #pragma unroll
        for (int n=0;n<4;n++) bb[n]=*reinterpret_cast<const s8vec*>(&Bs[(n0+n*16+ln)*72 + kk*32 + cq*8]);
        #pragma unroll
        for (int m=0;m<4;m++)
            #pragma unroll
            for (int n=0;n<4;n++)
                acc[m][n]=__builtin_amdgcn_mfma_f32_16x16x32_bf16(a[m],bb[n],acc[m][n],0,0,0);
    }
    bf16* Ab = Abuf + (size_t)l*WW*WW;
    // C/D layout: col = lane&15, row = (lane>>4)*4 + reg
    #pragma unroll
    for (int m=0;m<4;m++){
        #pragma unroll
        for (int r=0;r<4;r++){
            int w = mt*128 + m0 + m*16 + cq*4 + r;
            #pragma unroll
            for (int n=0;n<4;n++){
                int v = nt*128 + n0 + n*16 + ln;
                Ab[(size_t)w*WW + v] = f2b(acc[m][n][r]);
            }
        }
    }
}

// ---------------- K3: softmax stats (row + col) -- unchanged ----------------
__global__ __launch_bounds__(384) void k3_stats(
    const bf16* __restrict__ Abuf, float* __restrict__ rmax, float* __restrict__ irsum,
    float* __restrict__ cmax, float* __restrict__ icsum, int b)
{
    __shared__ float pm[6][64], ps[6][64];
    int t=threadIdx.x, l=blockIdx.x, seg=blockIdx.y;
    int bh=b*HH+l;
    const bf16* Ab = Abuf + (size_t)l*WW*WW;
    int lane=t&63, wid=t>>6;
    for (int w=seg*64+wid; w<seg*64+64; w+=6){
        const bf16* row=Ab+(size_t)w*WW;
        float m=-1e30f;
        for (int k=0;k<6;k++) m=fmaxf(m,b2f(row[lane+64*k]));
        for (int o=32;o;o>>=1) m=fmaxf(m,__shfl_xor(m,o,64));
        float s=0.f;
        for (int k=0;k<6;k++) s+=__expf(b2f(row[lane+64*k])-m);
        for (int o=32;o;o>>=1) s+=__shfl_xor(s,o,64);
        if (lane==0){ rmax[bh*WW+w]=m; irsum[bh*WW+w]=1.f/s; }
    }
    {
        int c=t&63, v=seg*64+c;
        float m=-1e30f;
        for (int w=wid*64; w<wid*64+64; w++) m=fmaxf(m,b2f(Ab[(size_t)w*WW+v]));
        float s=0.f;
        for (int w=wid*64; w<wid*64+64; w++) s+=__expf(b2f(Ab[(size_t)w*WW+v])-m);
        pm[wid][c]=m; ps[wid][c]=s;
    }
    __syncthreads();
    if (t<64){
        float M=-1e30f;
        for (int p=0;p<6;p++) M=fmaxf(M,pm[p][t]);
        float S=0.f;
        for (int p=0;p<6;p++) S+=ps[p][t]*__expf(pm[p][t]-M);
        cmax[bh*WW+seg*64+t]=M; icsum[bh*WW+seg*64+t]=1.f/S;
    }
}

// ---------------- K_mats: A -> P (in-place) + LT -- unchanged ----------------
__global__ __launch_bounds__(256) void k_mats(
    bf16* __restrict__ AP, bf16* __restrict__ LT,
    const float* __restrict__ rmax, const float* __restrict__ irsum,
    const float* __restrict__ cmax, const float* __restrict__ icsum, int b)
{
    int t=threadIdx.x, l=blockIdx.x, seg=blockIdx.y;
    int bh=b*HH+l;
    bf16* Ab  = AP + (size_t)l*WW*WW;
    bf16* LTb = LT + (size_t)l*WW*WW;
    const float* rm=rmax+(size_t)bh*WW; const float* ris=irsum+(size_t)bh*WW;
    const float* cm=cmax+(size_t)bh*WW; const float* cis=icsum+(size_t)bh*WW;
    int lane6=t&63;
    float cmv[6], civ[6];
    for (int s=0;s<6;s++){ cmv[s]=cm[s*64+lane6]; civ[s]=cis[s*64+lane6]; }
    for (int k=0;k<16;k++){
        int w = seg*64 + (t>>6) + 4*k;
        float rmw = rm[w], risw = ris[w];
        for (int s=0;s<6;s++){
            int v = s*64 + lane6;
            size_t idx = (size_t)w*WW + v;
            float a = b2f(Ab[idx]);
            Ab[idx]  = f2b(__expf(a - rmw)*risw);       // P[w][v] = M_r2l[w][v]
            LTb[idx] = f2b(__expf(a - cmv[s])*civ[s]);  // LT[w][v] = M_l2r[v][w]
        }
    }
}

// ---------------- K_trans: PT = P^T -- unchanged ----------------
__global__ __launch_bounds__(256) void k_trans(
    const bf16* __restrict__ Pm, bf16* __restrict__ PTm)
{
    __shared__ float tile[64][65];
    int t=threadIdx.x;
    int ti=blockIdx.x, tj=blockIdx.y, l=blockIdx.z;
    const bf16* Pb = Pm + (size_t)l*WW*WW;
    bf16* PTb = PTm + (size_t)l*WW*WW;
    for (int k=0;k<16;k++){
        int r=(t>>6)+4*k, c=t&63;
        tile[r][c] = b2f(Pb[(size_t)(ti*64+r)*WW + tj*64+c]);
    }
    __syncthreads();
    for (int k=0;k<16;k++){
        int r=(t>>6)+4*k, c=t&63;
        PTb[(size_t)(tj*64+r)*WW + ti*64+c] = f2b(tile[c][r]);
    }
}

// ---------------- K4: validity masks -- unchanged ----------------
__global__ __launch_bounds__(384) void k4_masks(
    const bf16* __restrict__ Pm, const bf16* __restrict__ LTm,
    float* __restrict__ mask_r2l, float* __restrict__ mask_l2r, int b)
{
    __shared__ float pa[6][64];
    int t=threadIdx.x, l=blockIdx.x, seg=blockIdx.y;
    int bh=b*HH+l;
    const bf16* Pb  = Pm  + (size_t)l*WW*WW;
    const bf16* LTb = LTm + (size_t)l*WW*WW;
    int lane=t&63, wid=t>>6;
    {
        int c=t&63, v=seg*64+c;
        float s=0.f;
        for (int w=wid*64; w<wid*64+64; w++) s+=b2f(Pb[(size_t)w*WW+v]);
        pa[wid][c]=s;
    }
    __syncthreads();
    if (t<64){
        float S=0.f;
        for (int p=0;p<6;p++) S+=pa[p][t];
        mask_r2l[bh*WW+seg*64+t]=(S>0.1f)?1.f:0.f;
    }
    for (int u=seg*64+wid; u<seg*64+64; u+=6){
        const bf16* row=LTb+(size_t)u*WW;
        float s=0.f;
        for (int k=0;k<6;k++) s+=b2f(row[lane+64*k]);
        for (int o=32;o;o>>=1) s+=__shfl_xor(s,o,64);
        if (lane==0) mask_l2r[bh*WW+u]=(s>0.1f)?1.f:0.f;
    }
}

// ---------------- K5m: out = x + coef * (M @ V^T) via MFMA ----------------
// grid (6 wtiles, HH), block 256 (4 waves; each wave 32x32 of the 64c x 64w tile)
// D[c][w] = sum_v VT[c][v] * M[w][v];   side0: M = P rows; side1: M[w][v] = LT[v][w]
// NOTE: launched BEFORE k_trans — V aliases the PT chunk.
__global__ __launch_bounds__(256) void k5m(
    const bf16* __restrict__ Msrc, const bf16* __restrict__ VT,
    const float* __restrict__ xadd, const float* __restrict__ coef,
    float* __restrict__ outp, int b, int side)
{
    __shared__ bf16 As[64*72];   // VT tile [c][v]
    __shared__ bf16 Bs[64*72];   // M tile  [w][v]
    int t=threadIdx.x;
    int wt=blockIdx.x, l=blockIdx.y;
    int w0=wt*64;
    int wv=t>>6, lane=t&63;
    int cb=(wv>>1)*32, wb=(wv&1)*32;
    int ln=lane&15, cq=lane>>4;
    f4vec acc[2][2];
    #pragma unroll
    for (int m=0;m<2;m++)
        #pragma unroll
        for (int n=0;n<2;n++) acc[m][n]=(f4vec){0.f,0.f,0.f,0.f};
    const bf16* Mb = Msrc + (size_t)l*WW*WW;

    for (int vt=0;vt<6;vt++){
        int v0=vt*64;
        __syncthreads();
        for (int i=0;i<2;i++){
            int lin=t+256*i; int c=lin>>3, c8=lin&7;
            *reinterpret_cast<uint4*>(&As[c*72+c8*8]) =
                *reinterpret_cast<const uint4*>(&VT[(size_t)c*HW + (size_t)l*WW + v0 + c8*8]);
        }
        if (side==0){
            for (int i=0;i<2;i++){
                int lin=t+256*i; int r=lin>>3, c8=lin&7;
                *reinterpret_cast<uint4*>(&Bs[r*72+c8*8]) =
                    *reinterpret_cast<const uint4*>(&Mb[(size_t)(w0+r)*WW + v0 + c8*8]);
            }
        } else {
            // Bs[w][v] = LT[v0+v][w0+w]  (global reads coalesced along w)
            int wl=t&63, j0=t>>6;
            for (int jj=0;jj<16;jj++){
                int j=j0+4*jj;
                Bs[wl*72+j] = Mb[(size_t)(v0+j)*WW + w0 + wl];
            }
        }
        __syncthreads();
        #pragma unroll
        for (int kk=0;kk<2;kk++){
            s8vec a[2], bb[2];
            #pragma unroll
            for (int m=0;m<2;m++) a[m]=*reinterpret_cast<const s8vec*>(&As[(cb+m*16+ln)*72+kk*32+cq*8]);
            #pragma unroll
            for (int n=0;n<2;n++) bb[n]=*reinterpret_cast<const s8vec*>(&Bs[(wb+n*16+ln)*72+kk*32+cq*8]);
            #pragma unroll
            for (int m=0;m<2;m++)
                #pragma unroll
                for (int n=0;n<2;n++)
                    acc[m][n]=__builtin_amdgcn_mfma_f32_16x16x32_bf16(a[m],bb[n],acc[m][n],0,0,0);
        }
    }
    const float* xb = xadd + (size_t)b*CHW + (size_t)l*WW + w0;
    float*      ob = outp + (size_t)b*CHW + (size_t)l*WW + w0;
    #pragma unroll
    for (int m=0;m<2;m++){
        #pragma unroll
        for (int r=0;r<4;r++){
            int c = cb + m*16 + cq*4 + r;
            float cf = coef[c];
            #pragma unroll
            for (int n=0;n<2;n++){
                int w = wb + n*16 + ln;
                ob[(size_t)c*HW + w] = xb[(size_t)c*HW + w] + cf*acc[m][n][r];
            }
        }
    }
}

// ---------------- K6: cycle loss GEMMs via MFMA -- unchanged ----------------
__global__ __launch_bounds__(256) void k6_mfma(
    const bf16* __restrict__ Pm, const bf16* __restrict__ LTm, const bf16* __restrict__ PTm,
    const float* __restrict__ mask_r2l, const float* __restrict__ mask_l2r,
    double* __restrict__ dsum, int b)
{
    __shared__ bf16 As[64*392];
    __shared__ bf16 Bs[64*72];
    int t=threadIdx.x;
    int wt=blockIdx.x, l=blockIdx.y, which=blockIdx.z;
    int w0=wt*64, bh=b*HH+l;
    const float* msk = which ? (mask_r2l+(size_t)bh*WW) : (mask_l2r+(size_t)bh*WW);

    if (which==0){
        const bf16* src = Pm + (size_t)l*WW*WW + (size_t)w0*WW;
        for (int i=0;i<12;i++){
            int lin = t + 256*i;
            int w = lin/48, c8 = lin - w*48;
            *reinterpret_cast<uint4*>(&As[w*392 + c8*8]) =
                *reinterpret_cast<const uint4*>(&src[(size_t)w*WW + c8*8]);
        }
    } else {
        const bf16* src = LTm + (size_t)l*WW*WW + w0;
        int wl = t&63, vb = t>>6;
        for (int i=0;i<96;i++){
            int v = vb + 4*i;
            As[wl*392 + v] = src[(size_t)v*WW + wl];
        }
    }

    const bf16* Bsrc = (which==0 ? LTm : PTm) + (size_t)l*WW*WW;
    int lane = t&63, wv = t>>6;
    int row32 = (wv>>1)*32, col32 = (wv&1)*32;
    int cn = lane&15, cq = lane>>4;

    float local = 0.f;
    for (int ut=0; ut<6; ut++){
        int u0 = ut*64;
        f4vec acc00={0,0,0,0}, acc01={0,0,0,0}, acc10={0,0,0,0}, acc11={0,0,0,0};
        for (int kt=0; kt<6; kt++){
            __syncthreads();
            for (int i=0;i<2;i++){
                int lin = t + 256*i;
                int u = lin>>3, c8 = lin&7;
                *reinterpret_cast<uint4*>(&Bs[u*72 + c8*8]) =
                    *reinterpret_cast<const uint4*>(&Bsrc[(size_t)(u0+u)*WW + kt*64 + c8*8]);
            }
            __syncthreads();
            for (int kk=0; kk<2; kk++){
                int ka = kt*64 + kk*32 + cq*8;
                int kb = kk*32 + cq*8;
                s8vec a0 = *reinterpret_cast<const s8vec*>(&As[(row32+cn)*392 + ka]);
                s8vec a1 = *reinterpret_cast<const s8vec*>(&As[(row32+16+cn)*392 + ka]);
                s8vec b0 = *reinterpret_cast<const s8vec*>(&Bs[(col32+cn)*72 + kb]);
                s8vec b1 = *reinterpret_cast<const s8vec*>(&Bs[(col32+16+cn)*72 + kb]);
                acc00 = __builtin_amdgcn_mfma_f32_16x16x32_bf16(a0,b0,acc00,0,0,0);
                acc01 = __builtin_amdgcn_mfma_f32_16x16x32_bf16(a0,b1,acc01,0,0,0);
                acc10 = __builtin_amdgcn_mfma_f32_16x16x32_bf16(a1,b0,acc10,0,0,0);
                acc11 = __builtin_amdgcn_mfma_f32_16x16x32_bf16(a1,b1,acc11,0,0,0);
            }
        }
        int ua = u0 + col32 + cn;
        float m0v = msk[ua], m1v = msk[ua+16];
        int wbase = w0 + row32 + cq*4;
        for (int r=0;r<4;r++){
            int wa = wbase + r, wb_ = wbase + 16 + r;
            local += m0v * fabsf(acc00[r] - ((ua==wa)?1.f:0.f));
            local += m1v * fabsf(acc01[r] - ((ua+16==wa)?1.f:0.f));
            local += m0v * fabsf(acc10[r] - ((ua==wb_)?1.f:0.f));
            local += m1v * fabsf(acc11[r] - ((ua+16==wb_)?1.f:0.f));
        }
    }
    for (int o=32;o;o>>=1) local += __shfl_xor(local,o,64);
    if (lane==0) atomicAdd(&dsum[0], (double)local);
}

// ---------------- K7: photometric loss + LR passthrough -- unchanged ----------------
__global__ __launch_bounds__(384) void k7_photo(
    const bf16* __restrict__ Pm, const bf16* __restrict__ LTm,
    const float* __restrict__ mask_r2l, const float* __restrict__ mask_l2r,
    const float* __restrict__ LRl, const float* __restrict__ LRr,
    float* __restrict__ out2, float* __restrict__ out3, double* __restrict__ dsum, int b)
{
    __shared__ float lrl[3*WW], lrr[3*WW];
    int t=threadIdx.x, l=blockIdx.x, seg=blockIdx.y;
    int bh=b*HH+l;
    for (int c=0;c<3;c++){
        size_t idx=((size_t)(b*3+c)*HH+l)*WW+t;
        float vl=LRl[idx], vr=LRr[idx];
        lrl[c*WW+t]=vl; lrr[c*WW+t]=vr;
        if (seg==0){ out2[idx]=vl; out3[idx]=vr; }
    }
    __syncthreads();
    const bf16* Pb  = Pm  + (size_t)l*WW*WW;
    const bf16* LTb = LTm + (size_t)l*WW*WW;
    int lane=t&63, wid=t>>6;
    float local=0.f;
    for (int w=seg*64+wid; w<seg*64+64; w+=6){
        const bf16* prow = Pb  + (size_t)w*WW;
        const bf16* lrow = LTb + (size_t)w*WW;
        float a0=0.f,a1=0.f,a2=0.f, d0=0.f,d1=0.f,d2=0.f;
        for (int k=0;k<6;k++){
            int v=lane+64*k;
            float mp=b2f(prow[v]), ml=b2f(lrow[v]);
            a0+=mp*lrr[v]; a1+=mp*lrr[WW+v]; a2+=mp*lrr[2*WW+v];
            d0+=ml*lrl[v]; d1+=ml*lrl[WW+v]; d2+=ml*lrl[2*WW+v];
        }
        for (int o=32;o;o>>=1){
            a0+=__shfl_xor(a0,o,64); a1+=__shfl_xor(a1,o,64); a2+=__shfl_xor(a2,o,64);
            d0+=__shfl_xor(d0,o,64); d1+=__shfl_xor(d1,o,64); d2+=__shfl_xor(d2,o,64);
        }
        if (lane==0){
            float mkL=mask_l2r[bh*WW+w], mkR=mask_r2l[bh*WW+w];
            local += mkL*(fabsf(lrl[w]-a0)+fabsf(lrl[WW+w]-a1)+fabsf(lrl[2*WW+w]-a2));
            local += mkR*(fabsf(lrr[w]-d0)+fabsf(lrr[WW+w]-d1)+fabsf(lrr[2*WW+w]-d2));
        }
    }
    if (lane==0) atomicAdd(&dsum[1],(double)local);
}

// ---------------- K8: smoothness losses -- unchanged ----------------
__global__ __launch_bounds__(384) void k8_smooth(
    const bf16* __restrict__ Pm, const bf16* __restrict__ LTm,
    double* __restrict__ dsum, int b)
{
    (void)b;
    int t=threadIdx.x, l=blockIdx.x, seg=blockIdx.y;
    const bf16* Pb  = Pm  + (size_t)l*WW*WW;
    const bf16* LTb = LTm + (size_t)l*WW*WW;
    int lane=t&63, wid=t>>6;
    bool hasnext = (l < HH-1);
    float lw=0.f, lh=0.f;
    for (int w=seg*64+wid; w<seg*64+64; w+=6){
        const bf16* p0  = Pb  + (size_t)w*WW;
        const bf16* lt0 = LTb + (size_t)w*WW;
        if (w < WW-1){
            const bf16* p1  = p0 + WW;
            const bf16* lt1 = lt0 + WW;
            for (int k=0;k<6;k++){
                int v=lane+64*k;
                if (v < WW-1){
                    lw += fabsf(b2f(p0[v]) - b2f(p1[v+1]));
                    lw += fabsf(b2f(lt0[v]) - b2f(lt1[v+1]));
                }
            }
        }
        if (hasnext){
            const bf16* pn  = p0  + (size_t)WW*WW;
            const bf16* ltn = lt0 + (size_t)WW*WW;
            for (int k=0;k<6;k++){
                int v=lane+64*k;
                lh += fabsf(b2f(p0[v]) - b2f(pn[v]));
                lh += fabsf(b2f(lt0[v]) - b2f(ltn[v]));
            }
        }
    }
    for (int o=32;o;o>>=1){ lw+=__shfl_xor(lw,o,64); lh+=__shfl_xor(lh,o,64); }
    if (lane==0){
        atomicAdd(&dsum[3],(double)lw);
        atomicAdd(&dsum[2],(double)lh);
    }
}

// ---------------- K9: final loss -- unchanged ----------------
__global__ void k9_final(const double* __restrict__ dsum, const float* __restrict__ lossin,
                         float* __restrict__ out4)
{
    if (threadIdx.x==0){
        double cyc  = dsum[0]/(double)((size_t)BB*HH*WW*WW);
        double photo= dsum[1]/(double)((size_t)BB*3*HH*WW);
        double lhv  = dsum[2]/(double)((size_t)BB*(HH-1)*WW*WW);
        double lwv  = dsum[3]/(double)((size_t)BB*HH*(WW-1)*(WW-1));
        double res  = (double)lossin[0] + 0.0025*(photo + 0.1*(lwv+lhv) + cyc);
        out4[0]=(float)res;
    }
}

extern "C" void kernel_launch(void* const* d_in, const int* in_sizes, int n_in,
                              void* d_out, int out_size, void* d_ws, size_t ws_size,
                              hipStream_t stream)
{
    (void)in_sizes; (void)n_in; (void)out_size; (void)ws_size;
    const float* x_l  = (const float*)d_in[0];
    const float* x_r  = (const float*)d_in[1];
    const float* LRl  = (const float*)d_in[2];
    const float* LRr  = (const float*)d_in[3];
    const float* lossi= (const float*)d_in[4];
    const float* nlw  = (const float*)d_in[5];
    const float* nlb  = (const float*)d_in[6];
    const float* nrw  = (const float*)d_in[7];
    const float* nrb  = (const float*)d_in[8];
    const float* lp1w = (const float*)d_in[9];
    const float* lp1b = (const float*)d_in[10];
    const float* rp1w = (const float*)d_in[11];
    const float* rp1b = (const float*)d_in[12];
    const float* lp2w = (const float*)d_in[13];
    const float* lp2b = (const float*)d_in[14];
    const float* rp2w = (const float*)d_in[15];
    const float* rp2b = (const float*)d_in[16];
    const float* beta = (const float*)d_in[17];
    const float* gamma= (const float*)d_in[18];

    bf16* Abuf = (bf16*)d_ws;             // A -> P in-place
    bf16* LTb  = Abuf + ACHUNK;
    bf16* PTb  = Abuf + 2*ACHUNK;
    float* wsf = (float*)((char*)d_ws + 3*ACHUNK*2);
    float* rmax=wsf, *irsum=wsf+SST, *cmax=wsf+2*SST, *icsum=wsf+3*SST;
    float* mask_r2l=wsf+4*SST, *mask_l2r=wsf+5*SST;
    double* dsum=(double*)(wsf+6*SST);
    // Q and V all alias the PT chunk (4*QELEMS <= ACHUNK); dead before k_trans runs.
    bf16* Qlb = PTb;
    bf16* Qrb = PTb + QELEMS;
    bf16* Vlb = PTb + 2*QELEMS;
    bf16* Vrb = PTb + 3*QELEMS;

    float* out  = (float*)d_out;
    float* out0 = out;
    float* out1 = out + (size_t)BB*CHW;
    float* out2 = out + 2*(size_t)BB*CHW;
    float* out3 = out2 + (size_t)BB*3*HW;
    float* out4 = out3 + (size_t)BB*3*HW;

    k0_zero<<<1,64,0,stream>>>(dsum);
    for (int b=0;b<BB;b++){
        k_qv<<<dim3(6,HH),256,0,stream>>>(x_l,x_r,nlw,nlb,nrw,nrb,
                                          lp1w,lp1b,rp1w,rp1b,lp2w,lp2b,rp2w,rp2b,
                                          Qlb,Qrb,Vlb,Vrb,b);
        k_attn<<<dim3(3,3,HH),256,0,stream>>>(Qlb,Qrb,Abuf);
        k3_stats<<<dim3(HH,6),384,0,stream>>>(Abuf,rmax,irsum,cmax,icsum,b);
        k_mats<<<dim3(HH,6),256,0,stream>>>(Abuf,LTb,rmax,irsum,cmax,icsum,b);
        k4_masks<<<dim3(HH,6),384,0,stream>>>(Abuf,LTb,mask_r2l,mask_l2r,b);
        k5m<<<dim3(6,HH),256,0,stream>>>(Abuf,Vrb,x_l,beta, out0,b,0);   // V consumed here,
        k5m<<<dim3(6,HH),256,0,stream>>>(LTb, Vlb,x_r,gamma,out1,b,1);   // BEFORE k_trans
        k_trans<<<dim3(6,6,HH),256,0,stream>>>(Abuf,PTb);
        k6_mfma<<<dim3(6,HH,2),256,0,stream>>>(Abuf,LTb,PTb,mask_r2l,mask_l2r,dsum,b);
        k7_photo<<<dim3(HH,6),384,0,stream>>>(Abuf,LTb,mask_r2l,mask_l2r,LRl,LRr,out2,out3,dsum,b);
        k8_smooth<<<dim3(HH,6),384,0,stream>>>(Abuf,LTb,dsum,b);
    }
    k9_final<<<1,64,0,stream>>>(dsum,lossi,out4);
}